// Round 1
// baseline (207.351 us; speedup 1.0000x reference)
//
#include <hip/hip_runtime.h>
#include <hip/hip_bf16.h>
#include <stdint.h>

// Problem constants
static constexpr int Mdim = 16384;  // T = B*N tokens
static constexpr int Ndim = 1024;   // D out
static constexpr int Kdim = 1024;   // D in
static constexpr int BM = 128, BN = 128, BK = 32;

typedef __attribute__((ext_vector_type(8))) __bf16 bf16x8;
typedef __attribute__((ext_vector_type(4))) float f32x4;
typedef __attribute__((ext_vector_type(4))) float float4v;
typedef __attribute__((ext_vector_type(8))) unsigned short ushort8;

__device__ inline unsigned short f2bf_rn(float f) {
    union { float f; uint32_t u; } v; v.f = f;
    uint32_t u = v.u;
    uint32_t r = u + 0x7FFFu + ((u >> 16) & 1u);
    return (unsigned short)(r >> 16);
}

// x (fp32) -> bf16, 8 elems/thread
__global__ __launch_bounds__(256) void cvt_x_kernel(const float* __restrict__ x,
                                                    unsigned short* __restrict__ a) {
    const size_t i = ((size_t)blockIdx.x * 256 + threadIdx.x) * 8;
    const float4v* xp = (const float4v*)(x + i);
    float4v v0 = xp[0], v1 = xp[1];
    ushort8 o;
    o[0] = f2bf_rn(v0[0]); o[1] = f2bf_rn(v0[1]); o[2] = f2bf_rn(v0[2]); o[3] = f2bf_rn(v0[3]);
    o[4] = f2bf_rn(v1[0]); o[5] = f2bf_rn(v1[1]); o[6] = f2bf_rn(v1[2]); o[7] = f2bf_rn(v1[3]);
    *(ushort8*)(a + i) = o;
}

// Wc = bf16(W_shared + W_expert), 8 elems/thread
__global__ __launch_bounds__(256) void cvt_w_kernel(const float* __restrict__ ws,
                                                    const float* __restrict__ we,
                                                    unsigned short* __restrict__ wc) {
    const size_t i = ((size_t)blockIdx.x * 256 + threadIdx.x) * 8;
    const float4v* p0 = (const float4v*)(ws + i);
    const float4v* p1 = (const float4v*)(we + i);
    float4v a0 = p0[0], a1 = p0[1], b0 = p1[0], b1 = p1[1];
    ushort8 o;
    o[0] = f2bf_rn(a0[0] + b0[0]); o[1] = f2bf_rn(a0[1] + b0[1]);
    o[2] = f2bf_rn(a0[2] + b0[2]); o[3] = f2bf_rn(a0[3] + b0[3]);
    o[4] = f2bf_rn(a1[0] + b1[0]); o[5] = f2bf_rn(a1[1] + b1[1]);
    o[6] = f2bf_rn(a1[2] + b1[2]); o[7] = f2bf_rn(a1[3] + b1[3]);
    *(ushort8*)(wc + i) = o;
}

__device__ inline void gload16(const void* g, void* l) {
    __builtin_amdgcn_global_load_lds((const __attribute__((address_space(1))) void*)g,
                                     (__attribute__((address_space(3))) void*)l,
                                     16, 0, 0);
}

// C[m][n] = sum_k A[m][k] * Bt[n][k] + bias[n]
// m97-style: 128x128 tile, BK=32, 4 waves each computing 64x64 via 4x4 grid of
// 16x16x32 bf16 MFMAs. Staging via global_load_lds width=16 (wave-uniform base
// + lane*16 => LDS tile must be packed row-major, K-fast, NO padding).
__global__ __launch_bounds__(256) void gemm_bt(const unsigned short* __restrict__ A,
                                               const unsigned short* __restrict__ Bt,
                                               const float* __restrict__ bias,
                                               float* __restrict__ C) {
    __shared__ unsigned short As[BM * BK];  // 8 KiB
    __shared__ unsigned short Bs[BN * BK];  // 8 KiB

    const int tid = threadIdx.x;
    const int wave = tid >> 6;
    const int lane = tid & 63;
    const int bn = blockIdx.x;  // 0..7
    const int bm = blockIdx.y;  // 0..127
    const int wm = (wave >> 1) * 64;  // wave's 64x64 sub-tile
    const int wn = (wave & 1) * 64;

    // Staging map: chunk cw (0..7) = 1 KiB = 16 rows; 2 calls x 4 waves.
    const int cw0 = wave, cw1 = 4 + wave;
    const int srow0 = cw0 * 16 + (lane >> 2);
    const int srow1 = cw1 * 16 + (lane >> 2);
    const int scol = (lane & 3) * 8;
    const unsigned short* gA0 = A + (size_t)(bm * BM + srow0) * Kdim + scol;
    const unsigned short* gA1 = A + (size_t)(bm * BM + srow1) * Kdim + scol;
    const unsigned short* gB0 = Bt + (size_t)(bn * BN + srow0) * Kdim + scol;
    const unsigned short* gB1 = Bt + (size_t)(bn * BN + srow1) * Kdim + scol;
    unsigned short* lA0 = As + cw0 * 512 + lane * 8;
    unsigned short* lA1 = As + cw1 * 512 + lane * 8;
    unsigned short* lB0 = Bs + cw0 * 512 + lane * 8;
    unsigned short* lB1 = Bs + cw1 * 512 + lane * 8;

    const int fr = lane & 15;        // row within a 16-tile (m for A, n for B)
    const int fk = (lane >> 4) * 8;  // k offset within BK

    f32x4 acc[4][4] = {};

    for (int kt = 0; kt < Kdim; kt += BK) {
        __syncthreads();  // protect LDS from previous iteration's readers
        gload16(gA0 + kt, lA0);
        gload16(gA1 + kt, lA1);
        gload16(gB0 + kt, lB0);
        gload16(gB1 + kt, lB1);
        __syncthreads();  // compiler drains vmcnt(0) before s_barrier

        bf16x8 af[4], bf[4];
#pragma unroll
        for (int i = 0; i < 4; ++i)
            af[i] = *(const bf16x8*)(As + (wm + i * 16 + fr) * BK + fk);
#pragma unroll
        for (int j = 0; j < 4; ++j)
            bf[j] = *(const bf16x8*)(Bs + (wn + j * 16 + fr) * BK + fk);
#pragma unroll
        for (int i = 0; i < 4; ++i)
#pragma unroll
            for (int j = 0; j < 4; ++j)
                acc[i][j] = __builtin_amdgcn_mfma_f32_16x16x32_bf16(af[i], bf[j], acc[i][j], 0, 0, 0);
    }

    // Epilogue: C/D layout col = lane&15, row = (lane>>4)*4 + reg  [m89-verified]
    const int fq = lane >> 4;
#pragma unroll
    for (int j = 0; j < 4; ++j) {
        const int col = bn * BN + wn + j * 16 + fr;
        const float bv = bias[col];
#pragma unroll
        for (int i = 0; i < 4; ++i) {
            const int row = bm * BM + wm + i * 16 + fq * 4;
            float* p = C + (size_t)row * Ndim + col;
#pragma unroll
            for (int r = 0; r < 4; ++r)
                p[(size_t)r * Ndim] = acc[i][j][r] + bv;
        }
    }
}

extern "C" void kernel_launch(void* const* d_in, const int* in_sizes, int n_in,
                              void* d_out, int out_size, void* d_ws, size_t ws_size,
                              hipStream_t stream) {
    // setup_inputs order: x, cond, mask, W_shared, W_expert, W_gate, bias
    // cond/mask/W_gate are mathematically dead (see analysis): routing is
    // positional, all experts share W_expert, normalized top-2 weights sum to 1.
    const float* x    = (const float*)d_in[0];
    const float* Wsh  = (const float*)d_in[3];
    const float* Wex  = (const float*)d_in[4];
    const float* bias = (const float*)d_in[6];
    float* out = (float*)d_out;

    unsigned short* Abf = (unsigned short*)d_ws;                  // 16384*1024 bf16 = 32 MiB
    unsigned short* Wbf = Abf + (size_t)Mdim * Kdim;              // 1024*1024 bf16 = 2 MiB

    hipLaunchKernelGGL(cvt_x_kernel, dim3((Mdim * Kdim) / (256 * 8)), dim3(256), 0, stream, x, Abf);
    hipLaunchKernelGGL(cvt_w_kernel, dim3((Ndim * Kdim) / (256 * 8)), dim3(256), 0, stream, Wsh, Wex, Wbf);
    hipLaunchKernelGGL(gemm_bt, dim3(Ndim / BN, Mdim / BM), dim3(256), 0, stream, Abf, Wbf, bias, out);
}

// Round 2
// 185.695 us; speedup vs baseline: 1.1166x; 1.1166x over previous
//
#include <hip/hip_runtime.h>
#include <hip/hip_bf16.h>
#include <stdint.h>

// out = x @ (W_shared + W_expert)^T + bias   (MoE collapses: positional routing,
// shared expert weights, normalized top-2 gate weights sum to 1)
static constexpr int Mdim = 16384;  // T = B*N tokens
static constexpr int Ndim = 1024;
static constexpr int Kdim = 1024;
static constexpr int BM = 128, BN = 128, BK = 64;  // BK = two 32-wide sub-tiles

typedef __attribute__((ext_vector_type(8))) __bf16 bf16x8;
typedef __attribute__((ext_vector_type(4))) float f32x4;
typedef __attribute__((ext_vector_type(8))) unsigned short ushort8;

__device__ inline unsigned short f2bf_rn(float f) {
    union { float f; uint32_t u; } v; v.f = f;
    uint32_t u = v.u;
    uint32_t r = u + 0x7FFFu + ((u >> 16) & 1u);
    return (unsigned short)(r >> 16);
}

// pack two fp32 -> bf16 pair (round-half-up: 1 add/elem; bias vs RNE is
// tie-cases only, absmax headroom is 3x)
__device__ inline uint32_t pack_bf2(float a, float b) {
    union { float f; uint32_t u; } ua, ub;
    ua.f = a; ub.f = b;
    uint32_t x = ua.u + 0x8000u;
    uint32_t y = ub.u + 0x8000u;
    return (x >> 16) | (y & 0xFFFF0000u);
}

// Wc = bf16(W_shared + W_expert), RNE, 8 elems/thread
__global__ __launch_bounds__(256) void cvt_w_kernel(const float* __restrict__ ws,
                                                    const float* __restrict__ we,
                                                    unsigned short* __restrict__ wc) {
    const size_t i = ((size_t)blockIdx.x * 256 + threadIdx.x) * 8;
    const f32x4* p0 = (const f32x4*)(ws + i);
    const f32x4* p1 = (const f32x4*)(we + i);
    f32x4 a0 = p0[0], a1 = p0[1], b0 = p1[0], b1 = p1[1];
    ushort8 o;
    o[0] = f2bf_rn(a0[0] + b0[0]); o[1] = f2bf_rn(a0[1] + b0[1]);
    o[2] = f2bf_rn(a0[2] + b0[2]); o[3] = f2bf_rn(a0[3] + b0[3]);
    o[4] = f2bf_rn(a1[0] + b1[0]); o[5] = f2bf_rn(a1[1] + b1[1]);
    o[6] = f2bf_rn(a1[2] + b1[2]); o[7] = f2bf_rn(a1[3] + b1[3]);
    *(ushort8*)(wc + i) = o;
}

__device__ inline void gload16(const void* g, void* l) {
    __builtin_amdgcn_global_load_lds((const __attribute__((address_space(1))) void*)g,
                                     (__attribute__((address_space(3))) void*)l,
                                     16, 0, 0);
}

// C[m][n] = sum_k bf16(X[m][k]) * Wc[n][k] + bias[n]
// A (=X) is fp32 in global; converted to bf16 in-register during staging.
// LDS layout: two independent BK=32 sub-tiles [s][row][32] -> 64-B row stride
// (identical bank behavior to the round-1 kernel). B staged via global_load_lds.
// Grid swizzle: bm-fastest => the 8 bn-blocks of one m-stripe share an XCD's L2.
__global__ __launch_bounds__(256, 4) void gemm_fused(const float* __restrict__ X,
                                                     const unsigned short* __restrict__ Bt,
                                                     const float* __restrict__ bias,
                                                     float* __restrict__ C) {
    __shared__ unsigned short As[2 * BM * 32];  // 16 KiB
    __shared__ unsigned short Bs[2 * BN * 32];  // 16 KiB

    const int tid = threadIdx.x;
    const int wave = tid >> 6;
    const int lane = tid & 63;
    const int bid = blockIdx.x;
    const int bm = bid & 127;   // fastest -> bid%8 == bm%8 -> same XCD per m-stripe
    const int bn = bid >> 7;
    const int wm = (wave >> 1) * 64;
    const int wn = (wave & 1) * 64;

    // ---- B staging map (per sub-tile: proven round-1 chunk pattern) ----
    const int cw0 = wave, cw1 = wave + 4;          // 1-KiB chunks (16 rows each)
    const int brow0 = cw0 * 16 + (lane >> 2);
    const int brow1 = cw1 * 16 + (lane >> 2);
    const int bcol = (lane & 3) * 8;
    const unsigned short* gB0 = Bt + (size_t)(bn * BN + brow0) * Kdim + bcol;
    const unsigned short* gB1 = Bt + (size_t)(bn * BN + brow1) * Kdim + bcol;
    unsigned short* lB0 = Bs + cw0 * 512 + lane * 8;   // + s*4096 per sub-tile
    unsigned short* lB1 = Bs + cw1 * 512 + lane * 8;

    // ---- A staging map (fp32 -> bf16 via VGPRs) ----
    const int arow = tid >> 3;        // 0..31 (plus u*32)
    const int acol4 = tid & 7;        // float4 index within 32-col sub-tile
    const float* gA = X + (size_t)(bm * BM + arow) * Kdim + acol4 * 4;
    unsigned short* lA = As + arow * 32 + acol4 * 4;   // + s*4096 + u*32*32

    const int fr = lane & 15;
    const int fq = lane >> 4;
    const int fk = fq * 8;

    f32x4 acc[4][4] = {};

    for (int kt = 0; kt < Kdim; kt += BK) {
        __syncthreads();  // protect LDS from previous iteration's readers
        // B: 4 chunks/thread via direct-to-LDS DMA
#pragma unroll
        for (int s = 0; s < 2; ++s) {
            gload16(gB0 + kt + s * 32, lB0 + s * 4096);
            gload16(gB1 + kt + s * 32, lB1 + s * 4096);
        }
        // A: 8 float4 loads, convert, 8-B LDS writes (conflict-free pattern)
        f32x4 av[2][4];
#pragma unroll
        for (int s = 0; s < 2; ++s)
#pragma unroll
            for (int u = 0; u < 4; ++u)
                av[s][u] = *(const f32x4*)(gA + (size_t)u * 32 * Kdim + kt + s * 32);
#pragma unroll
        for (int s = 0; s < 2; ++s)
#pragma unroll
            for (int u = 0; u < 4; ++u) {
                uint2 w;
                w.x = pack_bf2(av[s][u][0], av[s][u][1]);
                w.y = pack_bf2(av[s][u][2], av[s][u][3]);
                *(uint2*)(lA + s * 4096 + u * 1024) = w;
            }
        __syncthreads();

#pragma unroll
        for (int s = 0; s < 2; ++s) {
            bf16x8 af[4], bfr[4];
#pragma unroll
            for (int i = 0; i < 4; ++i)
                af[i] = *(const bf16x8*)(As + s * 4096 + (wm + i * 16 + fr) * 32 + fk);
#pragma unroll
            for (int j = 0; j < 4; ++j)
                bfr[j] = *(const bf16x8*)(Bs + s * 4096 + (wn + j * 16 + fr) * 32 + fk);
#pragma unroll
            for (int i = 0; i < 4; ++i)
#pragma unroll
                for (int j = 0; j < 4; ++j)
                    acc[i][j] = __builtin_amdgcn_mfma_f32_16x16x32_bf16(af[i], bfr[j], acc[i][j], 0, 0, 0);
        }
    }

    // Epilogue: C/D layout col = lane&15, row = (lane>>4)*4 + reg  [m89-verified]
#pragma unroll
    for (int j = 0; j < 4; ++j) {
        const int col = bn * BN + wn + j * 16 + fr;
        const float bv = bias[col];
#pragma unroll
        for (int i = 0; i < 4; ++i) {
            const int row = bm * BM + wm + i * 16 + fq * 4;
            float* p = C + (size_t)row * Ndim + col;
#pragma unroll
            for (int r = 0; r < 4; ++r)
                p[(size_t)r * Ndim] = acc[i][j][r] + bv;
        }
    }
}

extern "C" void kernel_launch(void* const* d_in, const int* in_sizes, int n_in,
                              void* d_out, int out_size, void* d_ws, size_t ws_size,
                              hipStream_t stream) {
    // inputs: x, cond, mask, W_shared, W_expert, W_gate, bias
    const float* x    = (const float*)d_in[0];
    const float* Wsh  = (const float*)d_in[3];
    const float* Wex  = (const float*)d_in[4];
    const float* bias = (const float*)d_in[6];
    float* out = (float*)d_out;

    unsigned short* Wbf = (unsigned short*)d_ws;  // 1024*1024 bf16 = 2 MiB

    hipLaunchKernelGGL(cvt_w_kernel, dim3((Ndim * Kdim) / (256 * 8)), dim3(256), 0, stream,
                       Wsh, Wex, Wbf);
    hipLaunchKernelGGL(gemm_fused, dim3((Mdim / BM) * (Ndim / BN)), dim3(256), 0, stream,
                       x, Wbf, bias, out);
}